// Round 8
// baseline (174.501 us; speedup 1.0000x reference)
//
#include <hip/hip_runtime.h>
#include <math.h>

#define BB 256
#define II 2048
#define CC 10
#define DOUT 16
#define COW 160          // C*DOUT
#define WELEMS (II*CC*DOUT*8)   // 2,621,440 W elements

typedef short  short8v __attribute__((ext_vector_type(8)));
typedef float  f32x4   __attribute__((ext_vector_type(4)));

__device__ __forceinline__ ushort f2bf(float x) {   // RNE f32 -> bf16 bits
    union { float f; unsigned u; } v; v.f = x;
    unsigned r = v.u + 0x7fff + ((v.u >> 16) & 1);
    return (ushort)(r >> 16);
}
__device__ __forceinline__ float bf2f(ushort h) {
    union { unsigned u; float f; } v; v.u = ((unsigned)h) << 16; return v.f;
}
__device__ __forceinline__ short8v pack8(float a0, float a1, float a2, float a3,
                                         float b0, float b1, float b2, float b3) {
    short8v r;
    r[0]=(short)f2bf(a0); r[1]=(short)f2bf(a1); r[2]=(short)f2bf(a2); r[3]=(short)f2bf(a3);
    r[4]=(short)f2bf(b0); r[5]=(short)f2bf(b1); r[6]=(short)f2bf(b2); r[7]=(short)f2bf(b3);
    return r;
}

// ---------------- W f32 -> bf16, once ----------------
__global__ __launch_bounds__(256)
void wcvt(const float* __restrict__ W, ushort* __restrict__ Wb)
{
    const size_t e = ((size_t)blockIdx.x * 256 + threadIdx.x) * 8;
    const float4 x0 = *(const float4*)(W + e);
    const float4 x1 = *(const float4*)(W + e + 4);
    short8v h = pack8(x0.x, x0.y, x0.z, x0.w, x1.x, x1.y, x1.z, x1.w);
    *(short8v*)(Wb + e) = h;
}

// ---------------- MODE 0 via MFMA (W pre-converted) ----------------
template<int LEN>
__global__ __launch_bounds__(256, 4)
void caps_pass0_mfma(const float* __restrict__ u, const ushort* __restrict__ Wb,
                     float* __restrict__ p)
{
    __shared__ ushort u_lds[64 * LEN * 8];   // [b][i^swz][d] bf16

    const int tid  = threadIdx.x;
    const int l    = tid & 63;
    const int quad = tid >> 6;
    const int bbase = blockIdx.y * 64;
    const int i0    = blockIdx.x * LEN;

    const int ROWF = LEN * 8;
    for (int e = tid * 4; e < 64 * ROWF; e += 1024) {
        const int rb = e / ROWF, er = e % ROWF;
        const int i = er >> 3, dh = er & 7;
        const float4 x = *(const float4*)(u + ((size_t)(bbase + rb) * II + i0 + i) * 8 + dh);
        ushort4 h;
        h.x = f2bf(x.x); h.y = f2bf(x.y); h.z = f2bf(x.z); h.w = f2bf(x.w);
        *(ushort4*)&u_lds[rb * ROWF + (i ^ (rb & 7)) * 8 + dh] = h;
    }
    __syncthreads();

    f32x4 acc[CC];
#pragma unroll
    for (int c = 0; c < CC; ++c) acc[c] = (f32x4){0.f, 0.f, 0.f, 0.f};

    const int arow = quad * 16 + (l & 15);
#pragma unroll
    for (int g = 0; g < LEN / 4; ++g) {
        const int ia = g * 4 + (l >> 4);
        const short8v af = *(const short8v*)&u_lds[arow * ROWF + ((ia ^ (arow & 7)) * 8)];
        const short8v* wg = (const short8v*)(Wb + (size_t)(i0 + ia) * (CC*128) + (l & 15) * 8);
#pragma unroll
        for (int c = 0; c < CC; ++c)
            acc[c] = __builtin_amdgcn_mfma_f32_16x16x32_bf16(af, wg[c * 16], acc[c], 0, 0, 0);
    }

    float* pp = p + (size_t)blockIdx.x * (BB * COW);
#pragma unroll
    for (int c = 0; c < CC; ++c)
#pragma unroll
        for (int r = 0; r < 4; ++r) {
            const int b = bbase + quad * 16 + (l >> 4) * 4 + r;
            pp[b * COW + c * DOUT + (l & 15)] = acc[c][r] * 0.1f;
        }
}

// ---------------- MODES 1/2 via MFMA, barrier-free iq loop ----------------
// All a_lds rows for wave wq lie in [64*wq, 64*wq+64) for writer (agreement),
// softmax, and fold reader alike -> intra-wave only -> no __syncthreads needed.
template<int MODE, int LEN>
__global__ __launch_bounds__(256, 3)
void caps_route(const float* __restrict__ u, const ushort* __restrict__ Wb,
                const float* __restrict__ v0, const float* __restrict__ v1,
                float* __restrict__ p)
{
    constexpr int RF = LEN * 8;              // bf16 elems per b-row
    __shared__ ushort u_lds[64 * RF];
    __shared__ float  a_lds[256 * 11];       // row = 64*wq + 4*(b16) + ii

    const int tid = threadIdx.x;
    const int l   = tid & 63;
    const int wq  = tid >> 6;                // wave's b-quadrant
    const int o4  = l & 15;                  // B/D col (b-rel), A row (o)
    const int g   = l >> 4;                  // k-group
    const int bbase = blockIdx.y * 64;
    const int i0    = blockIdx.x * LEN;

    // ---- stage u -> bf16 LDS ----
    for (int e = tid * 4; e < 64 * RF; e += 1024) {
        const int rb = e / RF, er = e % RF;
        const int i = er >> 3, dh = er & 7;
        const float4 x = *(const float4*)(u + ((size_t)(bbase + rb) * II + i0 + i) * 8 + dh);
        ushort4 h;
        h.x = f2bf(x.x); h.y = f2bf(x.y); h.z = f2bf(x.z); h.w = f2bf(x.w);
        *(ushort4*)&u_lds[rb * RF + (i ^ (rb & 7)) * 8 + dh] = h;
    }

    // ---- v regs: vreg[c][r] = v[b_lane, c, o=4g+r] ----
    const int brow  = wq * 16 + o4;
    const int b_abs = bbase + brow;
    float vreg[CC][4];
#pragma unroll
    for (int c = 0; c < CC; ++c)
#pragma unroll
        for (int r = 0; r < 4; ++r) {
            const int idx = b_abs * COW + c * DOUT + 4 * g + r;
            float x = v0[idx];
            if constexpr (MODE == 2) x += v1[idx];
            vreg[c][r] = x;
        }

    f32x4 acc[CC];
#pragma unroll
    for (int c = 0; c < CC; ++c) acc[c] = (f32x4){0.f, 0.f, 0.f, 0.f};
    const short8v zero8 = {0,0,0,0,0,0,0,0};
    const f32x4   zacc  = (f32x4){0.f, 0.f, 0.f, 0.f};

    __syncthreads();   // u_lds staging is cross-wave; the ONLY block barrier

    for (int iq = 0; iq < LEN / 4; ++iq) {
        const short8v u8 = *(const short8v*)
            &u_lds[brow * RF + (((iq * 4 + g) ^ (brow & 7)) * 8)];
        float uf[8];
#pragma unroll
        for (int e = 0; e < 8; ++e) uf[e] = bf2f((ushort)u8[e]);

        short8v w8[CC];
        // ---- u_hat MFMAs + agreement (results stay intra-wave) ----
#pragma unroll
        for (int c = 0; c < CC; ++c) {
            w8[c] = *(const short8v*)
                &Wb[((size_t)(i0 + iq * 4 + g) * CC + c) * 128 + o4 * 8];
            f32x4 uh[4];
#pragma unroll
            for (int j = 0; j < 4; ++j)
                uh[j] = __builtin_amdgcn_mfma_f32_16x16x32_bf16(
                    w8[c], (g == j) ? u8 : zero8, zacc, 0, 0, 0);
#pragma unroll
            for (int j = 0; j < 4; ++j) {
                float t = uh[j][0] * vreg[c][0] + uh[j][1] * vreg[c][1]
                        + uh[j][2] * vreg[c][2] + uh[j][3] * vreg[c][3];
                t += __shfl_xor(t, 16);
                t += __shfl_xor(t, 32);
                if (l < 16) a_lds[(64 * wq + 4 * l + j) * 11 + c] = t;
            }
        }
        __builtin_amdgcn_wave_barrier();

        // ---- softmax over c: row = tid (written by this wave) ----
        {
            float ex[CC];
            float s = 0.f;
#pragma unroll
            for (int c = 0; c < CC; ++c) { ex[c] = __expf(a_lds[tid * 11 + c]); s += ex[c]; }
            const float inv = 1.f / s;
#pragma unroll
            for (int c = 0; c < CC; ++c) a_lds[tid * 11 + c] = ex[c] * inv;
        }
        __builtin_amdgcn_wave_barrier();

        // ---- fold: acc_c += W * (cij .* u), full K over the i-quad ----
#pragma unroll
        for (int c = 0; c < CC; ++c) {
            const float cw = a_lds[(64 * wq + 4 * o4 + g) * 11 + c];
            const short8v bf = pack8(cw * uf[0], cw * uf[1], cw * uf[2], cw * uf[3],
                                     cw * uf[4], cw * uf[5], cw * uf[6], cw * uf[7]);
            acc[c] = __builtin_amdgcn_mfma_f32_16x16x32_bf16(w8[c], bf, acc[c], 0, 0, 0);
        }
        __builtin_amdgcn_wave_barrier();   // order a_lds reuse next iq
    }

    // ---- write partials: 4 g-lanes of one b cover 64B contiguous ----
    float* pp = p + (size_t)blockIdx.x * (BB * COW) + (size_t)b_abs * COW;
#pragma unroll
    for (int c = 0; c < CC; ++c)
        *(float4*)(pp + c * DOUT + 4 * g) =
            make_float4(acc[c][0], acc[c][1], acc[c][2], acc[c][3]);
}

// one wave per (b,c): sum partials over nsplit, squash, write vout
__global__ __launch_bounds__(64)
void reduce_squash(const float* __restrict__ p, int nsplit, float* __restrict__ vout)
{
    const int bc = blockIdx.x;
    const int b = bc / CC, c = bc % CC;
    const int l = threadIdx.x;
    const int o = l & 15, g = l >> 4;
    const float* base = p + (size_t)b * COW + c * DOUT + o;

    float s = 0.f;
    for (int sp = g; sp < nsplit; sp += 4)
        s += base[(size_t)sp * (BB * COW)];
    s += __shfl_xor(s, 16);
    s += __shfl_xor(s, 32);
    float sq = s * s;
    sq += __shfl_xor(sq, 1);
    sq += __shfl_xor(sq, 2);
    sq += __shfl_xor(sq, 4);
    sq += __shfl_xor(sq, 8);
    const float scale = (sq / (1.f + sq)) * rsqrtf(sq + 1e-9f);
    if (l < 16) vout[b * COW + c * DOUT + o] = s * scale;
}

template<int LEN>
static void launch_all(const float* u, const float* W, float* out,
                       float* v0, float* v1, ushort* Wb, float* p, int nsplit,
                       hipStream_t stream)
{
    dim3 grid(nsplit, BB / 64);
    wcvt<<<WELEMS / (256 * 8), 256, 0, stream>>>(W, Wb);
    caps_pass0_mfma<LEN><<<grid, 256, 0, stream>>>(u, Wb, p);
    reduce_squash<<<BB * CC, 64, 0, stream>>>(p, nsplit, v0);
    caps_route<1, LEN><<<grid, 256, 0, stream>>>(u, Wb, v0, v0, p);
    reduce_squash<<<BB * CC, 64, 0, stream>>>(p, nsplit, v1);
    caps_route<2, LEN><<<grid, 256, 0, stream>>>(u, Wb, v0, v1, p);
    reduce_squash<<<BB * CC, 64, 0, stream>>>(p, nsplit, out);
}

extern "C" void kernel_launch(void* const* d_in, const int* in_sizes, int n_in,
                              void* d_out, int out_size, void* d_ws, size_t ws_size,
                              hipStream_t stream)
{
    const float* u = (const float*)d_in[0];   // [256,2048,8]
    const float* W = (const float*)d_in[1];   // [2048,10,16,8]
    float* out = (float*)d_out;               // [256,10,16]

    const size_t SEG = (size_t)BB * COW;      // 40960 floats
    float*  v0 = (float*)d_ws;
    float*  v1 = v0 + SEG;
    ushort* Wb = (ushort*)(v1 + SEG);         // 2,621,440 ushorts = 32*SEG floats
    float*  p  = (float*)(Wb + WELEMS);

    const size_t avail_f = ws_size / sizeof(float);
    int nsplit = 256;
    while (nsplit > 32 && (34 + (size_t)nsplit) * SEG > avail_f) nsplit >>= 1;

    switch (nsplit) {
        case 256: launch_all<8>(u, W, out, v0, v1, Wb, p, 256, stream); break;
        case 128: launch_all<16>(u, W, out, v0, v1, Wb, p, 128, stream); break;
        case 64:  launch_all<32>(u, W, out, v0, v1, Wb, p, 64, stream); break;
        default:  launch_all<64>(u, W, out, v0, v1, Wb, p, 32, stream); break;
    }
}